// Round 3
// baseline (198.546 us; speedup 1.0000x reference)
//
#include <hip/hip_runtime.h>
#include <math.h>

namespace {

constexpr int Bc   = 16;    // batch
constexpr int Hc   = 16;    // heads
constexpr int Dc   = 128;   // head dim (K/Q)
constexpr int LVc  = 128;   // head dim (V)
constexpr int SPLc = 4;     // kv splits
constexpr int CH   = 16;    // token chunks per (b,s)
constexpr float LOGIT_CAP = 30.0f;
constexpr float SM_SCALE  = 0.08838834764831845f;   // 1/sqrt(128)

// ---------------------------------------------------------------------------
// Kernel 1: one block per (b, s, chunk). 256 threads = 16 head-groups x 16
// lanes. Thread t covers head h=t>>4, dims (t&15)*8..+8, i.e. float offset
// 8*t within the token's contiguous 2048-float (8 KB) row -> every K/V row
// is read as one fully-coalesced contiguous 8 KB block transaction group.
// Fixed softmax shift m=30 (logits capped at 30 by tanh) makes partials
// mergeable by pure addition. p = exp(30*tanh(z/30)-30) = exp(-60/(e^{z/15}+1)).
// ---------------------------------------------------------------------------
__launch_bounds__(256, 4)
__global__ void attn_partial(const float* __restrict__ q,
                             const float* __restrict__ kbuf,
                             const float* __restrict__ vbuf,
                             const int*   __restrict__ indptr,
                             const int*   __restrict__ indices,
                             const int*   __restrict__ nsplits,
                             float*       __restrict__ accW,
                             float*       __restrict__ esumW)
{
    const int bid = blockIdx.x;             // (b*S + s)*CH + c
    const int c   = bid % CH;
    const int bs  = bid / CH;
    const int s   = bs % SPLc;
    const int b   = bs / SPLc;

    const int t   = threadIdx.x;            // 0..255
    const int h   = t >> 4;
    const int sub = t & 15;

    const int kv_start = indptr[b];
    const int kv_len   = indptr[b + 1] - kv_start;
    const int ns       = nsplits[b];
    const int Ls       = kv_len / ns;       // 1024
    const int tok0     = kv_start + s * Ls;
    const int lo       = (int)(((long)Ls * c) / CH);
    const int hi       = (int)(((long)Ls * (c + 1)) / CH);
    const int cnt      = hi - lo;           // 64

    __shared__ int s_idx[256];
    for (int i = t; i < cnt; i += 256) s_idx[i] = indices[tok0 + lo + i];

    // q fragment: 8 floats of head h
    const float* qp = q + ((size_t)b * Hc + h) * Dc + sub * 8;
    const float4 q0 = *reinterpret_cast<const float4*>(qp);
    const float4 q1 = *reinterpret_cast<const float4*>(qp + 4);
    __syncthreads();

    float4 a0 = make_float4(0.f, 0.f, 0.f, 0.f);
    float4 a1 = make_float4(0.f, 0.f, 0.f, 0.f);
    float  esum = 0.f;

    #pragma unroll 4
    for (int l = 0; l < cnt; ++l) {
        const size_t base = (size_t)s_idx[l] * (Hc * Dc) + t * 8;
        const float4 k0 = *reinterpret_cast<const float4*>(kbuf + base);
        const float4 k1 = *reinterpret_cast<const float4*>(kbuf + base + 4);
        const float4 v0 = *reinterpret_cast<const float4*>(vbuf + base);
        const float4 v1 = *reinterpret_cast<const float4*>(vbuf + base + 4);

        float part = k0.x*q0.x + k0.y*q0.y + k0.z*q0.z + k0.w*q0.w
                   + k1.x*q1.x + k1.y*q1.y + k1.z*q1.z + k1.w*q1.w;
        part += __shfl_xor(part, 8);        // reduce within the 16-lane head group
        part += __shfl_xor(part, 4);
        part += __shfl_xor(part, 2);
        part += __shfl_xor(part, 1);

        // fused logit-cap + fixed shift
        const float e = __expf(part * (SM_SCALE / 15.0f));
        const float p = __expf(-60.0f / (e + 1.0f));
        esum += p;
        a0.x += p * v0.x; a0.y += p * v0.y; a0.z += p * v0.z; a0.w += p * v0.w;
        a1.x += p * v1.x; a1.y += p * v1.y; a1.z += p * v1.z; a1.w += p * v1.w;
    }

    // partials: accW[bid][h][128] (contiguous 8 KB store), esumW[bid][h]
    float* dst = accW + (size_t)bid * (Hc * Dc) + t * 8;
    *reinterpret_cast<float4*>(dst)     = a0;
    *reinterpret_cast<float4*>(dst + 4) = a1;
    if (sub == 0) esumW[bid * Hc + h] = esum;
}

// ---------------------------------------------------------------------------
// Kernel 2: one block per (b, h, s); sum 16 chunk-partials, normalize, lse.
// ---------------------------------------------------------------------------
__global__ void attn_reduce(const float* __restrict__ accW,
                            const float* __restrict__ esumW,
                            float*       __restrict__ out)
{
    const int bid = blockIdx.x;             // (b*H + h)*S + s
    const int s   = bid % SPLc;
    const int h   = (bid / SPLc) % Hc;
    const int b   = bid / (SPLc * Hc);
    const int d   = threadIdx.x;            // 0..127
    const int bs  = b * SPLc + s;

    float acc = 0.f;
    #pragma unroll
    for (int c = 0; c < CH; ++c)
        acc += accW[(size_t)(bs * CH + c) * (Hc * Dc) + h * Dc + d];

    float es = 0.f;
    #pragma unroll
    for (int c = 0; c < CH; ++c)
        es += esumW[(bs * CH + c) * Hc + h];

    out[(size_t)bid * LVc + d] = acc / es;
    if (d == 0)
        out[(size_t)Bc * Hc * SPLc * LVc + bid] = LOGIT_CAP + logf(es);
}

// ---------------------------------------------------------------------------
// Fallback (R1 single-kernel) if ws_size is too small.
// ---------------------------------------------------------------------------
__launch_bounds__(256, 4)
__global__ void decode_attn_fb(const float* __restrict__ q,
                               const float* __restrict__ kbuf,
                               const float* __restrict__ vbuf,
                               const int*   __restrict__ indptr,
                               const int*   __restrict__ indices,
                               const int*   __restrict__ nsplits,
                               float*       __restrict__ out)
{
    const int bid = blockIdx.x;
    const int s   = bid & (SPLc - 1);
    const int h   = (bid >> 2) & (Hc - 1);
    const int b   = bid >> 6;
    const int tid  = threadIdx.x;
    const int g    = tid >> 5;
    const int lane = tid & 31;

    const int kv_start = indptr[b];
    const int kv_len   = indptr[b + 1] - kv_start;
    const int ns       = nsplits[b];
    const int Ls       = kv_len / ns;
    const int tok0     = kv_start + s * Ls;

    __shared__ int   s_idx[1024];
    __shared__ float s_merge[8 * 128];
    __shared__ float s_esum[8];

    for (int i = tid; i < Ls; i += 256) s_idx[i] = indices[tok0 + i];
    const float4 q4 = *reinterpret_cast<const float4*>(
        q + ((size_t)b * Hc + h) * Dc + 4 * lane);
    __syncthreads();

    float4 acc = make_float4(0.f, 0.f, 0.f, 0.f);
    float  esum = 0.f;

    #pragma unroll 4
    for (int l = g; l < Ls; l += 8) {
        const int idx = s_idx[l];
        const size_t row = ((size_t)idx * Hc + h);
        const float4 k4 = *reinterpret_cast<const float4*>(kbuf + row * Dc  + 4 * lane);
        const float4 v4 = *reinterpret_cast<const float4*>(vbuf + row * LVc + 4 * lane);
        float part = q4.x * k4.x + q4.y * k4.y + q4.z * k4.z + q4.w * k4.w;
        part += __shfl_xor(part, 16);
        part += __shfl_xor(part, 8);
        part += __shfl_xor(part, 4);
        part += __shfl_xor(part, 2);
        part += __shfl_xor(part, 1);
        const float e = __expf(part * (SM_SCALE / 15.0f));
        const float p = __expf(-60.0f / (e + 1.0f));
        esum += p;
        acc.x += p * v4.x; acc.y += p * v4.y; acc.z += p * v4.z; acc.w += p * v4.w;
    }

    *reinterpret_cast<float4*>(&s_merge[g * 128 + 4 * lane]) = acc;
    if (lane == 0) s_esum[g] = esum;
    __syncthreads();
    #pragma unroll
    for (int off = 4; off >= 1; off >>= 1) {
        if (g < off) {
            float4 a = *reinterpret_cast<float4*>(&s_merge[g * 128 + 4 * lane]);
            const float4 cc = *reinterpret_cast<const float4*>(&s_merge[(g + off) * 128 + 4 * lane]);
            a.x += cc.x; a.y += cc.y; a.z += cc.z; a.w += cc.w;
            *reinterpret_cast<float4*>(&s_merge[g * 128 + 4 * lane]) = a;
            if (lane == 0) s_esum[g] += s_esum[g + off];
        }
        __syncthreads();
    }
    if (g == 0) {
        const float es  = s_esum[0];
        const float inv = 1.0f / es;
        float4 r = *reinterpret_cast<const float4*>(&s_merge[4 * lane]);
        r.x *= inv; r.y *= inv; r.z *= inv; r.w *= inv;
        float* outp = out + (((size_t)b * Hc + h) * SPLc + s) * LVc + 4 * lane;
        *reinterpret_cast<float4*>(outp) = r;
        if (lane == 0)
            out[(size_t)Bc * Hc * SPLc * LVc + ((size_t)b * Hc + h) * SPLc + s] =
                LOGIT_CAP + logf(es);
    }
}

} // anonymous namespace

extern "C" void kernel_launch(void* const* d_in, const int* in_sizes, int n_in,
                              void* d_out, int out_size, void* d_ws, size_t ws_size,
                              hipStream_t stream) {
    const float* q       = (const float*)d_in[0];
    const float* kbuf    = (const float*)d_in[1];
    const float* vbuf    = (const float*)d_in[2];
    const int*   indptr  = (const int*)d_in[3];
    const int*   indices = (const int*)d_in[4];
    const int*   nspl    = (const int*)d_in[5];
    float* outp = (float*)d_out;

    const size_t nPartialBlocks = (size_t)Bc * SPLc * CH;            // 1024
    const size_t accFloats  = nPartialBlocks * Hc * Dc;              // 2.10M
    const size_t esumFloats = nPartialBlocks * Hc;                   // 16K
    const size_t needed = (accFloats + esumFloats) * sizeof(float);  // ~8.45 MB

    if (ws_size >= needed) {
        float* accW  = (float*)d_ws;
        float* esumW = accW + accFloats;
        hipLaunchKernelGGL(attn_partial, dim3(Bc * SPLc * CH), dim3(256), 0, stream,
                           q, kbuf, vbuf, indptr, indices, nspl, accW, esumW);
        hipLaunchKernelGGL(attn_reduce, dim3(Bc * Hc * SPLc), dim3(128), 0, stream,
                           accW, esumW, outp);
    } else {
        hipLaunchKernelGGL(decode_attn_fb, dim3(Bc * Hc * SPLc), dim3(256), 0, stream,
                           q, kbuf, vbuf, indptr, indices, nspl, outp);
    }
}